// Round 1
// baseline (1411.336 us; speedup 1.0000x reference)
//
#include <hip/hip_runtime.h>
#include <math.h>

#define NJ 17
#define DD 128
#define XS 132     // padded row stride for X/X0 (float words)
#define LRS 260    // padded row stride for L/R (256 cols + 4 pad)
#define SS 20      // padded row stride for score rows
#define TOKE (NJ*DD)   // 2176 elements per token
#define NEGV -1.0e9f

// adjacency bitmasks: bit j of ADJM[i] set iff ADJ[i][j] (edges both dirs + diag)
__device__ __constant__ unsigned int ADJM[NJ] = {
    0x93u,    0x7u,     0xEu,     0xCu,     0x31u,    0x70u,    0x60u,
    0x181u,   0x4B80u,  0x700u,   0x600u,   0x1900u,  0x3800u,  0x3000u,
    0xC100u,  0x1C000u, 0x18000u
};

__device__ __forceinline__ float lrelu02(float u){ return fmaxf(u, 0.f) + 0.2f*fminf(u, 0.f); }
__device__ __forceinline__ float gelu_exact(float x){ return 0.5f*x*(1.f + erff(x*0.70710678118654752f)); }

// per-row LN stats over the 17x128 tile in sX -> sMU/sRS ; caller syncs
__device__ __forceinline__ void ln_stats(const float* sX, float* sMU, float* sRS, int t){
    if (t < 136){
        int g = t >> 3, w = t & 7;
        const float4* row = (const float4*)(sX + g*XS);
        float s = 0.f, q = 0.f;
        #pragma unroll
        for (int cc = 0; cc < 4; cc++){
            float4 v = row[w*4 + cc];
            s += v.x + v.y + v.z + v.w;
            q += v.x*v.x + v.y*v.y + v.z*v.z + v.w*v.w;
        }
        s += __shfl_xor(s, 1); s += __shfl_xor(s, 2); s += __shfl_xor(s, 4);
        q += __shfl_xor(q, 1); q += __shfl_xor(q, 2); q += __shfl_xor(q, 4);
        if (w == 0){
            float m = s * (1.f/128.f);
            float var = q * (1.f/128.f) - m*m;
            sMU[g] = m;
            sRS[g] = rsqrtf(var + 1e-5f);
        }
    }
}

__global__ __launch_bounds__(256, 2)
void appnp_kernel(const float* __restrict__ x,
                  const float* __restrict__ og, const float* __restrict__ ob,
                  const float* __restrict__ lg, const float* __restrict__ lb,
                  const float* __restrict__ aw, const float* __restrict__ ab,
                  const float* __restrict__ w1, const float* __restrict__ b1,
                  const float* __restrict__ w2, const float* __restrict__ b2,
                  const float* __restrict__ psw, const float* __restrict__ psb,
                  const float* __restrict__ vw, const float* __restrict__ vb,
                  float* __restrict__ out)
{
    __shared__ __align__(16) float smem[14068];
    float* sX  = smem;            // 17*132 = 2244 : x / xn (in-place LN)
    float* sX0 = smem + 2244;     // 2244 : x0
    float* sL  = smem + 4488;     // 17*260 = 4420 : l, later v
    float* sR  = smem + 8908;     // 4420 : r
    float* sS  = smem + 13328;    // 2*17*20 = 680 : scores/probs
    float* sMU = smem + 14008;    // 20
    float* sRS = smem + 14028;    // 20
    float* sK  = smem + 14048;    // 20 : skip gate per joint

    const int t = threadIdx.x;
    const long long base = (long long)blockIdx.x * TOKE;

    // ---- load token tile ----
    for (int idx = t; idx < TOKE; idx += 256){
        int j = idx >> 7, c = idx & 127;
        sX[j*XS + c] = x[base + idx];
    }
    __syncthreads();

    // ---- outer LN; copy to x0 ----
    ln_stats(sX, sMU, sRS, t);
    __syncthreads();
    for (int idx = t; idx < TOKE; idx += 256){
        int j = idx >> 7, c = idx & 127;
        float v = (sX[j*XS + c] - sMU[j]) * sRS[j] * og[c] + ob[c];
        sX[j*XS + c] = v;
        sX0[j*XS + c] = v;
    }
    __syncthreads();

    for (int it = 0; it < 4; it++){
        // ---- inner LN (in place: X becomes xn) ----
        ln_stats(sX, sMU, sRS, t);
        __syncthreads();
        for (int idx = t; idx < TOKE; idx += 256){
            int j = idx >> 7, c = idx & 127;
            sX[j*XS + c] = (sX[j*XS + c] - sMU[j]) * sRS[j] * lg[c] + lb[c];
        }
        __syncthreads();

        // ---- l = xn@w1+b1, r = xn@w2+b2  (thread t owns column t of 256) ----
        {
            const int c = t;
            float accl[NJ], accr[NJ];
            float bb1 = b1[c], bb2 = b2[c];
            #pragma unroll
            for (int i = 0; i < NJ; i++){ accl[i] = bb1; accr[i] = bb2; }
            for (int k = 0; k < DD; k += 4){
                float a0 = w1[(k+0)*256 + c], a1 = w1[(k+1)*256 + c];
                float a2 = w1[(k+2)*256 + c], a3 = w1[(k+3)*256 + c];
                float d0 = w2[(k+0)*256 + c], d1 = w2[(k+1)*256 + c];
                float d2 = w2[(k+2)*256 + c], d3 = w2[(k+3)*256 + c];
                #pragma unroll
                for (int i = 0; i < NJ; i++){
                    float4 xv = *(const float4*)(sX + i*XS + k);
                    accl[i] += xv.x*a0 + xv.y*a1 + xv.z*a2 + xv.w*a3;
                    accr[i] += xv.x*d0 + xv.y*d1 + xv.z*d2 + xv.w*d3;
                }
            }
            #pragma unroll
            for (int i = 0; i < NJ; i++){ sL[i*LRS + c] = accl[i]; sR[i*LRS + c] = accr[i]; }
        }
        __syncthreads();

        // ---- attention scores (sparse: only adjacent pairs) ----
        {
            const float pb = psb[0];
            const float4* pp = (const float4*)psw;
            for (int e = t; e < 578; e += 256){
                int h = e / 289; int rem = e - h*289;
                int i = rem / 17; int j = rem - i*17;
                float sc;
                if ((ADJM[i] >> j) & 1u){
                    const float4* lp = (const float4*)(sL + i*LRS + h*128);
                    const float4* rp = (const float4*)(sR + j*LRS + h*128);
                    float acc = 0.f;
                    #pragma unroll
                    for (int d4 = 0; d4 < 32; d4++){
                        float4 lv = lp[d4], rv = rp[d4], pv = pp[d4];
                        acc += lrelu02(lv.x+rv.x)*pv.x + lrelu02(lv.y+rv.y)*pv.y
                             + lrelu02(lv.z+rv.z)*pv.z + lrelu02(lv.w+rv.w)*pv.w;
                    }
                    sc = acc + pb;
                } else {
                    sc = NEGV;
                }
                sS[h*340 + i*SS + j] = sc;
            }
        }
        __syncthreads();

        // ---- v = xn@vw+vb (t<128) ; softmax rows (t 128..161) ; skip gate (t 162..178) ----
        if (t < 128){
            const int c = t;
            float acc[NJ];
            float bb = vb[c];
            #pragma unroll
            for (int i = 0; i < NJ; i++) acc[i] = bb;
            for (int k = 0; k < DD; k += 4){
                float a0 = vw[(k+0)*128 + c], a1 = vw[(k+1)*128 + c];
                float a2 = vw[(k+2)*128 + c], a3 = vw[(k+3)*128 + c];
                #pragma unroll
                for (int i = 0; i < NJ; i++){
                    float4 xv = *(const float4*)(sX + i*XS + k);
                    acc[i] += xv.x*a0 + xv.y*a1 + xv.z*a2 + xv.w*a3;
                }
            }
            #pragma unroll
            for (int i = 0; i < NJ; i++) sL[i*LRS + c] = acc[i];  // reuse sL as V
        } else if (t < 162){
            int r = t - 128; int h = r / 17; int i = r - h*17;
            float* sp = sS + h*340 + i*SS;
            float m = sp[0];
            #pragma unroll
            for (int j = 1; j < NJ; j++) m = fmaxf(m, sp[j]);
            float p[NJ]; float sum = 0.f;
            #pragma unroll
            for (int j = 0; j < NJ; j++){ p[j] = expf(sp[j] - m); sum += p[j]; }
            float inv = 1.f / sum;
            #pragma unroll
            for (int j = 0; j < NJ; j++) sp[j] = p[j] * inv;
        } else if (t < 179){
            int i = t - 162;
            float acc = 0.f;
            for (int c2 = 0; c2 < DD; c2++) acc += sX[i*XS + c2] * aw[c2];
            sK[i] = 1.f / (1.f + expf(-(acc + ab[0])));
        }
        __syncthreads();

        // ---- o = softmax @ v, gelu, blend with skip/x0 -> new x ----
        for (int idx = t; idx < TOKE; idx += 256){
            int i = idx >> 7, c = idx & 127, h = c >> 6;
            const float* srow = sS + h*340 + i*SS;
            float acc = 0.f;
            #pragma unroll
            for (int j = 0; j < NJ; j++) acc += srow[j] * sL[j*LRS + c];
            float g = gelu_exact(acc);
            float sk = sK[i];
            sX[i*XS + c] = (1.f - sk)*g + sk*sX0[i*XS + c];
        }
        __syncthreads();
    }

    // ---- store ----
    for (int idx = t; idx < TOKE; idx += 256){
        int j = idx >> 7, c = idx & 127;
        out[base + idx] = sX[j*XS + c];
    }
}

extern "C" void kernel_launch(void* const* d_in, const int* in_sizes, int n_in,
                              void* d_out, int out_size, void* d_ws, size_t ws_size,
                              hipStream_t stream) {
    const float* x   = (const float*)d_in[0];
    const float* og  = (const float*)d_in[1];
    const float* ob  = (const float*)d_in[2];
    const float* lg  = (const float*)d_in[3];
    const float* lb  = (const float*)d_in[4];
    const float* aw  = (const float*)d_in[5];
    const float* ab  = (const float*)d_in[6];
    const float* w1  = (const float*)d_in[7];
    const float* b1  = (const float*)d_in[8];
    const float* w2  = (const float*)d_in[9];
    const float* b2  = (const float*)d_in[10];
    const float* psw = (const float*)d_in[11];
    const float* psb = (const float*)d_in[12];
    const float* vw  = (const float*)d_in[13];
    const float* vb  = (const float*)d_in[14];
    float* out = (float*)d_out;

    int BT = in_sizes[0] / TOKE;   // 3888 tokens
    appnp_kernel<<<dim3(BT), dim3(256), 0, stream>>>(
        x, og, ob, lg, lb, aw, ab, w1, b1, w2, b2, psw, psb, vw, vb, out);
}